// Round 2
// baseline (49.300 us; speedup 1.0000x reference)
//
#include <hip/hip_runtime.h>

// WaveletLoss: loss = mean|d| + Σ_{3 Haar levels} mean|dH|+mean|dV|+mean|dD|,
// d = pred - target (Haar is linear).  96 images of 512x512 fp32 = 6144
// contiguous strips of 8 rows x 512 cols (16 KB per input each).
//
// R7: R6's doubled grid, WITHOUT the launch_bounds register cap.
//  - R6 FAILED: __launch_bounds__(256,8) caps VGPRs at 64 < the pipeline's
//    peak liveness (16 x f32x4 buffers + pointers) -> compiler spilled to
//    scratch. Scratch ops increment vmcnt, so the hand-counted
//    s_waitcnt vmcnt(8) no longer meant "buffer A landed" -> garbage.
//    RULE: counted-vmcnt pipelines are incompatible with any VGPR cap that
//    forces spills; every vmcnt-incrementing op must be ours.
//  - 2048 persistent blocks x 256 threads (SPB=3): 8 blocks/CU x 4 waves
//    = 32 waves/CU = 100% of wave slots at VGPR<=64 (R5 measured 44).
//    R5's 1024 blocks gave only 16 waves/CU, OccupancyPercent ~30%.
//  - Thread t owns a 4x4 patch (px = t>>1, pyl = t&1): 8 x global_load_dwordx4
//    per strip, issued via inline asm so the compiler CANNOT serialize them.
//  - Register double-buffer + counted s_waitcnt vmcnt(8): while computing
//    strip k from buffer A, buffer B's 8 loads are in flight.
//  - sched_barrier(0) after each waitcnt (compiler hoists register-only
//    consumers past inline-asm waitcnt otherwise).
//  - Level 3 needs the 2x2 group of per-thread cA2: quad {4k..4k+3} holds it
//    -> __shfl_xor(1)/__shfl_xor(2), every lane computes the same s3 (w3/4).

typedef float f32x4 __attribute__((ext_vector_type(4)));

#define IMG  512
#define NBLK 2048
#define SPB  3                                   // 6144 strips / 2048 blocks
#define STRIP_BYTES (8 * IMG * 4)                // 16384
#define ITER_BYTES  ((size_t)NBLK * STRIP_BYTES) // 32 MB per pipeline step

__device__ __forceinline__ float haar_quad(float a, float b, float c, float d,
                                           float& det) {
    det += (fabsf(a + b - c - d) + fabsf(a - b + c - d) + fabsf(a - b - c + d)) * 0.5f;
    return (a + b + c + d) * 0.5f;
}

__global__ __launch_bounds__(256) void wavelet_loss_kernel(
    const float* __restrict__ pred, const float* __restrict__ target,
    float* __restrict__ out)
{
    const int t   = threadIdx.x;
    const int px  = t >> 1;    // patch col 0..127
    const int pyl = t & 1;     // patch row-pair 0..1

    // Per-thread byte offset of its patch row 0 (and row 2) within the strip.
    const size_t thr0 = ((size_t)(pyl * 4 + 0) * IMG + (size_t)px * 4) * 4;
    const size_t thr2 = thr0 + 2 * IMG * 4;
    const size_t sb   = (size_t)blockIdx.x * STRIP_BYTES;

    // Four running per-lane pointers (rows 0/2 of P and T); rows 1/3 via
    // offset:2048 (one 512-float row = 2048 B, fits the 13-bit signed imm).
    const float* pP0 = (const float*)((const char*)pred   + sb + thr0);
    const float* pP2 = (const float*)((const char*)pred   + sb + thr2);
    const float* pT0 = (const float*)((const char*)target + sb + thr0);
    const float* pT2 = (const float*)((const char*)target + sb + thr2);

#define ISSUE(P0, P1, P2, P3, T0, T1, T2, T3)                                              \
    asm volatile("global_load_dwordx4 %0, %1, off"             : "=v"(P0) : "v"(pP0));     \
    asm volatile("global_load_dwordx4 %0, %1, off offset:2048" : "=v"(P1) : "v"(pP0));     \
    asm volatile("global_load_dwordx4 %0, %1, off"             : "=v"(P2) : "v"(pP2));     \
    asm volatile("global_load_dwordx4 %0, %1, off offset:2048" : "=v"(P3) : "v"(pP2));     \
    asm volatile("global_load_dwordx4 %0, %1, off"             : "=v"(T0) : "v"(pT0));     \
    asm volatile("global_load_dwordx4 %0, %1, off offset:2048" : "=v"(T1) : "v"(pT0));     \
    asm volatile("global_load_dwordx4 %0, %1, off"             : "=v"(T2) : "v"(pT2));     \
    asm volatile("global_load_dwordx4 %0, %1, off offset:2048" : "=v"(T3) : "v"(pT2))

#define BUMP()                                                   \
    pP0 = (const float*)((const char*)pP0 + ITER_BYTES);         \
    pP2 = (const float*)((const char*)pP2 + ITER_BYTES);         \
    pT0 = (const float*)((const char*)pT0 + ITER_BYTES);         \
    pT2 = (const float*)((const char*)pT2 + ITER_BYTES)

    const float w0 = 1.f / 25165824.f;
    const float w1 = 1.f / 6291456.f;
    const float w2 = 1.f / 1572864.f;
    const float w3 = 0.25f / 393216.f;   // all 4 quad lanes add the same s3

    float acc = 0.f;

#define COMPUTE(P0, P1, P2, P3, T0, T1, T2, T3) do {                               \
    f32x4 d0 = P0 - T0, d1 = P1 - T1, d2 = P2 - T2, d3 = P3 - T3;                  \
    float s0 = 0.f;                                                                \
    _Pragma("unroll")                                                              \
    for (int c = 0; c < 4; ++c)                                                    \
        s0 += fabsf(d0[c]) + fabsf(d1[c]) + fabsf(d2[c]) + fabsf(d3[c]);           \
    float s1 = 0.f;                                                                \
    float a00 = haar_quad(d0[0], d0[1], d1[0], d1[1], s1);                         \
    float a01 = haar_quad(d0[2], d0[3], d1[2], d1[3], s1);                         \
    float a10 = haar_quad(d2[0], d2[1], d3[0], d3[1], s1);                         \
    float a11 = haar_quad(d2[2], d2[3], d3[2], d3[3], s1);                         \
    float s2 = 0.f;                                                                \
    float cA2 = haar_quad(a00, a01, a10, a11, s2);                                 \
    float vC = __shfl_xor(cA2, 1, 64);  /* vertical partner  */                    \
    float vB = __shfl_xor(cA2, 2, 64);  /* horizontal partner */                   \
    float vD = __shfl_xor(vC,  2, 64);  /* diagonal           */                   \
    float s3 = (fabsf(cA2 + vB - vC - vD) + fabsf(cA2 - vB + vC - vD)              \
              + fabsf(cA2 - vB - vC + vD)) * 0.5f;                                 \
    acc += s0 * w0 + s1 * w1 + s2 * w2 + s3 * w3;                                  \
} while (0)

    f32x4 PA0, PA1, PA2, PA3, TA0, TA1, TA2, TA3;   // buffer A
    f32x4 PB0, PB1, PB2, PB3, TB0, TB1, TB2, TB3;   // buffer B

    // SPB == 3, straight-line double-buffered pipeline:
    ISSUE(PA0, PA1, PA2, PA3, TA0, TA1, TA2, TA3);  // strip 0
    BUMP();
    ISSUE(PB0, PB1, PB2, PB3, TB0, TB1, TB2, TB3);  // strip 1
    BUMP();

    asm volatile("s_waitcnt vmcnt(8)" ::: "memory"); // strip 0 landed
    __builtin_amdgcn_sched_barrier(0);
    COMPUTE(PA0, PA1, PA2, PA3, TA0, TA1, TA2, TA3);

    ISSUE(PA0, PA1, PA2, PA3, TA0, TA1, TA2, TA3);  // strip 2
    asm volatile("s_waitcnt vmcnt(8)" ::: "memory"); // strip 1 landed
    __builtin_amdgcn_sched_barrier(0);
    COMPUTE(PB0, PB1, PB2, PB3, TB0, TB1, TB2, TB3);

    asm volatile("s_waitcnt vmcnt(0)" ::: "memory"); // strip 2 landed
    __builtin_amdgcn_sched_barrier(0);
    COMPUTE(PA0, PA1, PA2, PA3, TA0, TA1, TA2, TA3);

    // ---- final reduction: wave-64 shuffle, LDS for 4 waves, 1 atomic/block
    #pragma unroll
    for (int off = 32; off > 0; off >>= 1)
        acc += __shfl_down(acc, off, 64);

    __shared__ float wsum[4];
    const int lane = t & 63;
    const int wid  = t >> 6;
    if (lane == 0) wsum[wid] = acc;
    __syncthreads();
    if (t == 0)
        atomicAdd(out, wsum[0] + wsum[1] + wsum[2] + wsum[3]);
}

extern "C" void kernel_launch(void* const* d_in, const int* in_sizes, int n_in,
                              void* d_out, int out_size, void* d_ws, size_t ws_size,
                              hipStream_t stream) {
    const float* pred   = (const float*)d_in[0];
    const float* target = (const float*)d_in[1];
    float* out = (float*)d_out;

    // d_out is poisoned once before timing and never re-poisoned; zero it.
    hipMemsetAsync(out, 0, sizeof(float), stream);

    wavelet_loss_kernel<<<NBLK, 256, 0, stream>>>(pred, target, out);
}

// Round 3
// 35.304 us; speedup vs baseline: 1.3964x; 1.3964x over previous
//
#include <hip/hip_runtime.h>

// WaveletLoss: loss = mean|d| + Σ_{3 Haar levels} mean|dH|+mean|dV|+mean|dD|,
// d = pred - target (Haar is linear).  96 images of 512x512 fp32 = 6144
// contiguous strips of 8 rows x 512 cols (16 KB per input each).
//
// R8: R5's proven pipeline (1024 blocks, SPB=6, 40.7 us) + clean output path.
//  - R6 (launch_bounds cap) FAILED: VGPR cap -> scratch spills increment
//    vmcnt -> hand-counted s_waitcnt vmcnt(8) invalid -> garbage.
//  - R7 (2048 blocks) REGRESSED 40.7->49.3: occupancy 30->44% but hbm_gbps
//    FLAT. No pipe saturated (HBM 38%, L2 14%, VALU 7%): the kernel sits at
//    a latency x queue-capacity ceiling (~19.3 GB/s/CU delivered, already
//    1.6x the m13 copy benchmark's per-CU read rate). Wave-level MLP is not
//    the lever; extra streams only add contention.
//  - R8 change: drop hipMemsetAsync + 1024 same-address cross-XCD atomicAdd
//    (serialize at one L2 line). Blocks plain-store partials to d_ws; a
//    second 1-block kernel sums 1024 floats and STORES out (no zeroing
//    needed). Graph node count unchanged (memset swapped for tiny kernel).
//
//  - Thread t owns a 4x4 patch (px = t>>1, pyl = t&1): 8 x global_load_dwordx4
//    per strip, issued via inline asm so the compiler CANNOT serialize them.
//  - Register double-buffer + counted s_waitcnt vmcnt(8): while computing
//    strip k from buffer A, buffer B's 8 loads are in flight.
//  - sched_barrier(0) after each waitcnt (compiler hoists register-only
//    consumers past inline-asm waitcnt otherwise).
//  - Level 3 needs the 2x2 group of per-thread cA2: quad {4k..4k+3} holds it
//    -> __shfl_xor(1)/__shfl_xor(2), every lane computes the same s3 (w3/4).

typedef float f32x4 __attribute__((ext_vector_type(4)));

#define IMG  512
#define NBLK 1024
#define SPB  6                                   // 6144 strips / 1024 blocks
#define STRIP_BYTES (8 * IMG * 4)                // 16384
#define ITER_BYTES  ((size_t)NBLK * STRIP_BYTES) // 16 MB per pipeline step

__device__ __forceinline__ float haar_quad(float a, float b, float c, float d,
                                           float& det) {
    det += (fabsf(a + b - c - d) + fabsf(a - b + c - d) + fabsf(a - b - c + d)) * 0.5f;
    return (a + b + c + d) * 0.5f;
}

__global__ __launch_bounds__(256) void wavelet_loss_kernel(
    const float* __restrict__ pred, const float* __restrict__ target,
    float* __restrict__ partial)
{
    const int t   = threadIdx.x;
    const int px  = t >> 1;    // patch col 0..127
    const int pyl = t & 1;     // patch row-pair 0..1

    // Per-thread byte offset of its patch row 0 (and row 2) within the strip.
    const size_t thr0 = ((size_t)(pyl * 4 + 0) * IMG + (size_t)px * 4) * 4;
    const size_t thr2 = thr0 + 2 * IMG * 4;
    const size_t sb   = (size_t)blockIdx.x * STRIP_BYTES;

    // Four running per-lane pointers (rows 0/2 of P and T); rows 1/3 via
    // offset:2048 (one 512-float row = 2048 B, fits the 13-bit signed imm).
    const float* pP0 = (const float*)((const char*)pred   + sb + thr0);
    const float* pP2 = (const float*)((const char*)pred   + sb + thr2);
    const float* pT0 = (const float*)((const char*)target + sb + thr0);
    const float* pT2 = (const float*)((const char*)target + sb + thr2);

#define ISSUE(P0, P1, P2, P3, T0, T1, T2, T3)                                              \
    asm volatile("global_load_dwordx4 %0, %1, off"             : "=v"(P0) : "v"(pP0));     \
    asm volatile("global_load_dwordx4 %0, %1, off offset:2048" : "=v"(P1) : "v"(pP0));     \
    asm volatile("global_load_dwordx4 %0, %1, off"             : "=v"(P2) : "v"(pP2));     \
    asm volatile("global_load_dwordx4 %0, %1, off offset:2048" : "=v"(P3) : "v"(pP2));     \
    asm volatile("global_load_dwordx4 %0, %1, off"             : "=v"(T0) : "v"(pT0));     \
    asm volatile("global_load_dwordx4 %0, %1, off offset:2048" : "=v"(T1) : "v"(pT0));     \
    asm volatile("global_load_dwordx4 %0, %1, off"             : "=v"(T2) : "v"(pT2));     \
    asm volatile("global_load_dwordx4 %0, %1, off offset:2048" : "=v"(T3) : "v"(pT2))

#define BUMP()                                                   \
    pP0 = (const float*)((const char*)pP0 + ITER_BYTES);         \
    pP2 = (const float*)((const char*)pP2 + ITER_BYTES);         \
    pT0 = (const float*)((const char*)pT0 + ITER_BYTES);         \
    pT2 = (const float*)((const char*)pT2 + ITER_BYTES)

    const float w0 = 1.f / 25165824.f;
    const float w1 = 1.f / 6291456.f;
    const float w2 = 1.f / 1572864.f;
    const float w3 = 0.25f / 393216.f;   // all 4 quad lanes add the same s3

    float acc = 0.f;

#define COMPUTE(P0, P1, P2, P3, T0, T1, T2, T3) do {                               \
    f32x4 d0 = P0 - T0, d1 = P1 - T1, d2 = P2 - T2, d3 = P3 - T3;                  \
    float s0 = 0.f;                                                                \
    _Pragma("unroll")                                                              \
    for (int c = 0; c < 4; ++c)                                                    \
        s0 += fabsf(d0[c]) + fabsf(d1[c]) + fabsf(d2[c]) + fabsf(d3[c]);           \
    float s1 = 0.f;                                                                \
    float a00 = haar_quad(d0[0], d0[1], d1[0], d1[1], s1);                         \
    float a01 = haar_quad(d0[2], d0[3], d1[2], d1[3], s1);                         \
    float a10 = haar_quad(d2[0], d2[1], d3[0], d3[1], s1);                         \
    float a11 = haar_quad(d2[2], d2[3], d3[2], d3[3], s1);                         \
    float s2 = 0.f;                                                                \
    float cA2 = haar_quad(a00, a01, a10, a11, s2);                                 \
    float vC = __shfl_xor(cA2, 1, 64);  /* vertical partner  */                    \
    float vB = __shfl_xor(cA2, 2, 64);  /* horizontal partner */                   \
    float vD = __shfl_xor(vC,  2, 64);  /* diagonal           */                   \
    float s3 = (fabsf(cA2 + vB - vC - vD) + fabsf(cA2 - vB + vC - vD)              \
              + fabsf(cA2 - vB - vC + vD)) * 0.5f;                                 \
    acc += s0 * w0 + s1 * w1 + s2 * w2 + s3 * w3;                                  \
} while (0)

    f32x4 PA0, PA1, PA2, PA3, TA0, TA1, TA2, TA3;   // buffer A
    f32x4 PB0, PB1, PB2, PB3, TB0, TB1, TB2, TB3;   // buffer B

    ISSUE(PA0, PA1, PA2, PA3, TA0, TA1, TA2, TA3);  // strip 0
    BUMP();

    for (int sp = 0; sp < SPB / 2; ++sp) {
        ISSUE(PB0, PB1, PB2, PB3, TB0, TB1, TB2, TB3);   // strip 2sp+1
        BUMP();
        asm volatile("s_waitcnt vmcnt(8)" ::: "memory");  // buffer A landed
        __builtin_amdgcn_sched_barrier(0);
        COMPUTE(PA0, PA1, PA2, PA3, TA0, TA1, TA2, TA3);

        if (sp + 1 < SPB / 2) {
            ISSUE(PA0, PA1, PA2, PA3, TA0, TA1, TA2, TA3);  // strip 2sp+2
            BUMP();
            asm volatile("s_waitcnt vmcnt(8)" ::: "memory"); // buffer B landed
        } else {
            asm volatile("s_waitcnt vmcnt(0)" ::: "memory");
        }
        __builtin_amdgcn_sched_barrier(0);
        COMPUTE(PB0, PB1, PB2, PB3, TB0, TB1, TB2, TB3);
    }

    // ---- final reduction: wave-64 shuffle, LDS for 4 waves, PLAIN STORE of
    // the block partial (no atomic, no pre-zeroed output needed).
    #pragma unroll
    for (int off = 32; off > 0; off >>= 1)
        acc += __shfl_down(acc, off, 64);

    __shared__ float wsum[4];
    const int lane = t & 63;
    const int wid  = t >> 6;
    if (lane == 0) wsum[wid] = acc;
    __syncthreads();
    if (t == 0)
        partial[blockIdx.x] = wsum[0] + wsum[1] + wsum[2] + wsum[3];
}

// 1 block x 256 threads: sum 1024 partials, STORE the scalar loss.
__global__ __launch_bounds__(256) void reduce_partials_kernel(
    const float* __restrict__ partial, float* __restrict__ out)
{
    const int t = threadIdx.x;
    float v = partial[t] + partial[t + 256] + partial[t + 512] + partial[t + 768];
    #pragma unroll
    for (int off = 32; off > 0; off >>= 1)
        v += __shfl_down(v, off, 64);

    __shared__ float wsum[4];
    if ((t & 63) == 0) wsum[t >> 6] = v;
    __syncthreads();
    if (t == 0)
        out[0] = wsum[0] + wsum[1] + wsum[2] + wsum[3];
}

extern "C" void kernel_launch(void* const* d_in, const int* in_sizes, int n_in,
                              void* d_out, int out_size, void* d_ws, size_t ws_size,
                              hipStream_t stream) {
    const float* pred   = (const float*)d_in[0];
    const float* target = (const float*)d_in[1];
    float* out     = (float*)d_out;
    float* partial = (float*)d_ws;   // 1024 floats = 4 KB of workspace

    wavelet_loss_kernel<<<NBLK, 256, 0, stream>>>(pred, target, partial);
    reduce_partials_kernel<<<1, 256, 0, stream>>>(partial, out);
}